// Round 7
// baseline (2233.484 us; speedup 1.0000x reference)
//
#include <hip/hip_runtime.h>

// ---------------------------------------------------------------------------
// HeteroFraudGNN on MI355X — round 7: breadth-parallel gather (edge-parallel
// ds_add_f32), async BTl stage, round-5 store pattern.
// k_fused: 64 rows/block, 512 thr, LDS ~72.5KB -> 2 blocks/CU.
//   P0: edge window -> sE, off -> sO/sInv, zero sAf(f32), stage sB=BTr,
//       issue dense A-frag loads. bar
//   P1: issue chunk-0 gather loads (8thr/edge) -> dense MFMA -> ds_add_f32
//       into sAf -> remaining chunks -> issue BTl->regs. bar
//   P2: write BTl regs -> sB. bar
//   P3: agg MFMA, A-frags read from sAf(f32), scale 1/deg + cvt in regs. bar
//   P4: bn/relu -> h16 out-tile (reuse sAf). bar
//   P5: coalesced stores, 64B/thread (round-5 pattern, no write amplification).
// ---------------------------------------------------------------------------

#define NUv   100000
#define NTv   400000
#define Ev    400000
#define Hv    128
#define NLv   3
#define HID2v 64
#define EPSv  1e-5f
#define SECAP 2048

typedef _Float16 h16;
typedef __attribute__((ext_vector_type(8))) _Float16 f16x8;
typedef __attribute__((ext_vector_type(4))) float    f32x4;

#define WS_NEED (280u * 1024u * 1024u)
__device__ __attribute__((aligned(256))) static unsigned char g_ws[WS_NEED];

__device__ __forceinline__ int imin(int a, int b) { return a < b ? a : b; }
// swizzled byte offset inside a [n][128] h16 LDS tile (256B rows)
__device__ __forceinline__ int swz(int n, int kbyte) {
  return n * 256 + (kbyte ^ ((n & 7) << 4));
}

// ---------------------------------------------------------------- CSR build
__global__ __launch_bounds__(256) void k_count(const int* __restrict__ d0,
                                               const int* __restrict__ d1,
                                               int* __restrict__ c0,
                                               int* __restrict__ c1, int e) {
  int t = blockIdx.x * 256 + threadIdx.x;
  if (t < e) {
    atomicAdd(c0 + d0[t], 1);
    atomicAdd(c1 + d1[t], 1);
  }
}

__global__ __launch_bounds__(256) void k_blocksum(const int* __restrict__ cnt,
                                                  int* __restrict__ bs, int n) {
  __shared__ int red[256];
  int base = blockIdx.x * 2048 + threadIdx.x * 8;
  int s = 0;
#pragma unroll
  for (int j = 0; j < 8; j++) {
    int p = base + j;
    if (p < n) s += cnt[p];
  }
  red[threadIdx.x] = s;
  __syncthreads();
  for (int st = 128; st > 0; st >>= 1) {
    if (threadIdx.x < st) red[threadIdx.x] += red[threadIdx.x + st];
    __syncthreads();
  }
  if (threadIdx.x == 0) bs[blockIdx.x] = red[0];
}

__global__ __launch_bounds__(256) void k_scansmall(int* __restrict__ bs, int g) {
  __shared__ int lds[256];
  int t = threadIdx.x;
  int v = (t < g) ? bs[t] : 0;
  lds[t] = v;
  __syncthreads();
  for (int st = 1; st < 256; st <<= 1) {
    int x = (t >= st) ? lds[t - st] : 0;
    __syncthreads();
    lds[t] += x;
    __syncthreads();
  }
  if (t < g) bs[t] = lds[t] - v;  // exclusive
}

__global__ __launch_bounds__(256) void k_scanfinal(const int* __restrict__ cnt,
                                                   const int* __restrict__ bs,
                                                   int* __restrict__ off,
                                                   int* __restrict__ cur, int n) {
  __shared__ int lds[256];
  int t = threadIdx.x;
  int base = blockIdx.x * 2048 + t * 8;
  int v[8], pre[8];
  int tsum = 0;
#pragma unroll
  for (int j = 0; j < 8; j++) {
    int p = base + j;
    v[j] = (p < n) ? cnt[p] : 0;
    pre[j] = tsum;
    tsum += v[j];
  }
  lds[t] = tsum;
  __syncthreads();
  for (int st = 1; st < 256; st <<= 1) {
    int x = (t >= st) ? lds[t - st] : 0;
    __syncthreads();
    lds[t] += x;
    __syncthreads();
  }
  int texcl = lds[t] - tsum;
  int boff = bs[blockIdx.x];
#pragma unroll
  for (int j = 0; j < 8; j++) {
    int p = base + j;
    if (p < n) {
      int o = boff + texcl + pre[j];
      off[p] = o;
      cur[p] = o;
      if (p == n - 1) off[n] = o + v[j];
    }
  }
}

__global__ __launch_bounds__(256) void k_fill(const int* __restrict__ s0,
                                              const int* __restrict__ d0,
                                              const int* __restrict__ s1,
                                              const int* __restrict__ d1,
                                              int* __restrict__ cur0,
                                              int* __restrict__ cur1,
                                              int* __restrict__ ss0,
                                              int* __restrict__ ss1, int e) {
  int t = blockIdx.x * 256 + threadIdx.x;
  if (t < e) {
    int p = atomicAdd(cur0 + d0[t], 1);
    ss0[p] = s0[t];
    int q = atomicAdd(cur1 + d1[t], 1);
    ss1[q] = s1[t];
  }
}

// ------------------------------------------------------- weight / bn prep
__global__ __launch_bounds__(256) void k_wt(const float* __restrict__ Wl,
                                            const float* __restrict__ Wr,
                                            const float* __restrict__ W1,
                                            h16* __restrict__ WlT,
                                            h16* __restrict__ WrT,
                                            h16* __restrict__ W1T) {
  int t = blockIdx.x * 256 + threadIdx.x;
  const int NW = NLv * 2 * Hv * Hv;  // 196608
  if (t < NW) {
    int mat = t / (Hv * Hv);
    int n = (t / Hv) % Hv;
    int k = t % Hv;
    WlT[t] = (h16)Wl[(size_t)mat * Hv * Hv + (size_t)k * Hv + n];
    WrT[t] = (h16)Wr[(size_t)mat * Hv * Hv + (size_t)k * Hv + n];
  } else if (t < NW + HID2v * Hv) {
    int u = t - NW;
    int n = u / Hv;
    int k = u % Hv;
    W1T[u] = (h16)W1[(size_t)k * HID2v + n];
  }
}

__global__ __launch_bounds__(256) void k_bn(const float* __restrict__ g,
                                            const float* __restrict__ b,
                                            const float* __restrict__ m,
                                            const float* __restrict__ v,
                                            float* __restrict__ sc,
                                            float* __restrict__ sh) {
  int t = blockIdx.x * 256 + threadIdx.x;
  if (t < NLv * 2 * Hv) {
    float inv = rsqrtf(v[t] + EPSv);
    float s = g[t] * inv;
    sc[t] = s;
    sh[t] = b[t] - m[t] * s;
  }
}

// ------------------------------------------------------------- embeddings
__global__ __launch_bounds__(256) void k_embed(const int* __restrict__ xu,
                                               const int* __restrict__ xt,
                                               const float* __restrict__ eu,
                                               const float* __restrict__ et,
                                               h16* __restrict__ hu,
                                               h16* __restrict__ ht) {
  int t = blockIdx.x * 256 + threadIdx.x;
  int row = t >> 4;
  int c = (t & 15) * 8;
  if (row >= NUv + NTv) return;
  const float* src;
  h16* dst;
  if (row < NUv) {
    src = eu + (size_t)xu[row] * Hv;
    dst = hu + (size_t)row * Hv;
  } else {
    int r2 = row - NUv;
    src = et + (size_t)xt[r2] * Hv;
    dst = ht + (size_t)r2 * Hv;
  }
  float4 v0 = *(const float4*)(src + c);
  float4 v1 = *(const float4*)(src + c + 4);
  f16x8 o;
  o[0] = (h16)v0.x; o[1] = (h16)v0.y; o[2] = (h16)v0.z; o[3] = (h16)v0.w;
  o[4] = (h16)v1.x; o[5] = (h16)v1.y; o[6] = (h16)v1.z; o[7] = (h16)v1.w;
  *(f16x8*)(dst + c) = o;
}

// --------------------------------------------------- fused gather+GEMM+bn
// OUT = relu(bn(seg_mean(SRC via off/ss) @ BTl + DENSE @ BTr + bl))
// mfma_f32_16x16x32_f16 convention (learn_hip m89):
//   A frag: a[j] = A[lane&15][kblk*32 + (lane>>4)*8 + j]
//   B frag: b[j] = B[kblk*32 + (lane>>4)*8 + j][lane&15]  (B^T stored [N][K])
//   D frag: d[r] = D[(lane>>4)*4 + r][lane&15]
// Wave w of 8: row-tile rt=w>>1 (16 rows), col-half nh=w&1 (nf = nh*4+j).
__global__ __launch_bounds__(512, 4) void k_fused(const h16* __restrict__ SRC,
                                                  const h16* __restrict__ DENSE,
                                                  const int* __restrict__ off,
                                                  const int* __restrict__ ss,
                                                  const h16* __restrict__ BTl,
                                                  const h16* __restrict__ BTr,
                                                  const float* __restrict__ bl,
                                                  const float* __restrict__ sc,
                                                  const float* __restrict__ sh,
                                                  h16* __restrict__ C, int M) {
  __shared__ __align__(16) unsigned char sB[128 * 256];  // 32 KB B^T (h16, swz)
  __shared__ __align__(16) float sAf[64 * 128];          // 32 KB f32 agg accum
  __shared__ int   sE[SECAP];                            // 8 KB edge window
  __shared__ int   sO[65];
  __shared__ float sInv[64];

  int t = threadIdx.x;
  int base = blockIdx.x * 64;
  int l = t & 63;
  int lm = l & 15, lk = l >> 4;
  int rt = (t >> 6) >> 1, nh = (t >> 6) & 1;
  int rowBase = base + rt * 16;

  // ---- P0: edge range (broadcast loads)
  int mEnd = imin(base + 64, M);
  int e0 = off[base];
  int e1 = off[mEnd];
  int eblk = e1 - e0;

  if (t <= 64) sO[t] = off[imin(base + t, M)];
  if (t < 64) {
    int rr = base + t;
    int d = (rr < M) ? (off[rr + 1] - off[rr]) : 0;
    sInv[t] = 1.f / (float)(d > 1 ? d : 1);
  }
  // zero sAf (dense interleaved b128 writes)
#pragma unroll
  for (int j = 0; j < 4; j++)
    *(f32x4*)(&sAf[(t + j * 512) * 4]) = (f32x4){0.f, 0.f, 0.f, 0.f};
  // stage sB = BTr (coalesced 64B/thread, swizzled)
  {
    const h16* bsrc = BTr + t * 32;
    f16x8 b0 = *(const f16x8*)(bsrc + 0);
    f16x8 b1 = *(const f16x8*)(bsrc + 8);
    f16x8 b2 = *(const f16x8*)(bsrc + 16);
    f16x8 b3 = *(const f16x8*)(bsrc + 24);
    int n = t >> 2;
    int kb = (t & 3) * 64;
    *(f16x8*)(sB + swz(n, kb + 0)) = b0;
    *(f16x8*)(sB + swz(n, kb + 16)) = b1;
    *(f16x8*)(sB + swz(n, kb + 32)) = b2;
    *(f16x8*)(sB + swz(n, kb + 48)) = b3;
  }
  // stage sE (coalesced, contiguous window)
  for (int i = t; i < eblk && i < SECAP; i += 512) sE[i] = ss[e0 + i];
  // dense A-frags issued here (latency overlaps barrier + gather)
  int ar = imin(rowBase + lm, M - 1);
  const h16* arow = DENSE + (size_t)ar * Hv;
  f16x8 ad0 = *(const f16x8*)(arow + 0 * 32 + lk * 8);
  f16x8 ad1 = *(const f16x8*)(arow + 1 * 32 + lk * 8);
  f16x8 ad2 = *(const f16x8*)(arow + 2 * 32 + lk * 8);
  f16x8 ad3 = *(const f16x8*)(arow + 3 * 32 + lk * 8);
  __syncthreads();

  // ---- P1a: issue chunk-0 gather loads (8 threads/edge, 16 f32 cols each)
  int slice = t & 7;
  int csbyte = slice * 64;  // byte offset of 16-f32 slice within a 512B row
  int ei0 = t >> 3;
  f16x8 g0a, g0b;
  int grow0 = -1;
  if (ei0 < eblk) {
    int srcIdx = (ei0 < SECAP) ? sE[ei0] : ss[e0 + ei0];
    const h16* sp = SRC + (size_t)srcIdx * Hv + slice * 16;
    g0a = *(const f16x8*)(sp);
    g0b = *(const f16x8*)(sp + 8);
    int ge = e0 + ei0;
    int lo = 0;
#pragma unroll
    for (int st = 32; st >= 1; st >>= 1)
      if (lo + st <= 63 && sO[lo + st] <= ge) lo += st;
    grow0 = lo;
  }

  // ---- P1b: dense MFMA (overlaps gather load latency)
  f32x4 acc[4];
#pragma unroll
  for (int j = 0; j < 4; j++) acc[j] = (f32x4){0.f, 0.f, 0.f, 0.f};
  {
    f16x8 ads[4] = {ad0, ad1, ad2, ad3};
#pragma unroll
    for (int s = 0; s < 4; s++) {
#pragma unroll
      for (int j = 0; j < 4; j++) {
        int nf = nh * 4 + j;
        f16x8 b = *(const f16x8*)(sB + swz(nf * 16 + lm, s * 64 + lk * 16));
        acc[j] = __builtin_amdgcn_mfma_f32_16x16x32_f16(ads[s], b, acc[j], 0, 0, 0);
      }
    }
  }

  // ---- P1c: chunk-0 atomic adds (rotated col order to spread banks)
  if (grow0 >= 0) {
    float vals[16];
#pragma unroll
    for (int j = 0; j < 8; j++) {
      vals[j] = (float)g0a[j];
      vals[8 + j] = (float)g0b[j];
    }
    int sw = (grow0 & 7) << 4;
    int wbase = grow0 * 128;
#pragma unroll
    for (int j = 0; j < 16; j++) {
      int jj = (j + t) & 15;
      int byte = ((csbyte + ((jj >> 2) << 4)) ^ sw) + ((jj & 3) << 2);
      atomicAdd(&sAf[wbase + (byte >> 2)], vals[jj]);
    }
  }

  // ---- P1d: remaining chunks (independent iterations)
  for (int ei = ei0 + 64; ei < eblk; ei += 64) {
    int srcIdx = (ei < SECAP) ? sE[ei] : ss[e0 + ei];
    const h16* sp = SRC + (size_t)srcIdx * Hv + slice * 16;
    f16x8 ga = *(const f16x8*)(sp);
    f16x8 gb = *(const f16x8*)(sp + 8);
    int ge = e0 + ei;
    int lo = 0;
#pragma unroll
    for (int st = 32; st >= 1; st >>= 1)
      if (lo + st <= 63 && sO[lo + st] <= ge) lo += st;
    float vals[16];
#pragma unroll
    for (int j = 0; j < 8; j++) {
      vals[j] = (float)ga[j];
      vals[8 + j] = (float)gb[j];
    }
    int sw = (lo & 7) << 4;
    int wbase = lo * 128;
#pragma unroll
    for (int j = 0; j < 16; j++) {
      int jj = (j + t) & 15;
      int byte = ((csbyte + ((jj >> 2) << 4)) ^ sw) + ((jj & 3) << 2);
      atomicAdd(&sAf[wbase + (byte >> 2)], vals[jj]);
    }
  }

  // ---- P1e: async-stage BTl: issue loads now, write after barrier (T14)
  const h16* bsrc2 = BTl + t * 32;
  f16x8 bw0 = *(const f16x8*)(bsrc2 + 0);
  f16x8 bw1 = *(const f16x8*)(bsrc2 + 8);
  f16x8 bw2 = *(const f16x8*)(bsrc2 + 16);
  f16x8 bw3 = *(const f16x8*)(bsrc2 + 24);
  __syncthreads();  // sAf complete; sB(BTr) reads done

  // ---- P2: write BTl -> sB
  {
    int n = t >> 2;
    int kb = (t & 3) * 64;
    *(f16x8*)(sB + swz(n, kb + 0)) = bw0;
    *(f16x8*)(sB + swz(n, kb + 16)) = bw1;
    *(f16x8*)(sB + swz(n, kb + 32)) = bw2;
    *(f16x8*)(sB + swz(n, kb + 48)) = bw3;
  }
  __syncthreads();

  // ---- P3: agg MFMA; A-frags straight from sAf (scale + cvt in regs)
  {
    int row = rt * 16 + lm;
    float inv = sInv[row];
    int sw = (row & 7) << 4;
    const unsigned char* rbase = (const unsigned char*)sAf + row * 512;
#pragma unroll
    for (int s = 0; s < 4; s++) {
      int cb = s * 128 + lk * 32;
      f32x4 f0 = *(const f32x4*)(rbase + ((cb) ^ sw));
      f32x4 f1 = *(const f32x4*)(rbase + ((cb + 16) ^ sw));
      f16x8 a;
      a[0] = (h16)(f0[0] * inv); a[1] = (h16)(f0[1] * inv);
      a[2] = (h16)(f0[2] * inv); a[3] = (h16)(f0[3] * inv);
      a[4] = (h16)(f1[0] * inv); a[5] = (h16)(f1[1] * inv);
      a[6] = (h16)(f1[2] * inv); a[7] = (h16)(f1[3] * inv);
#pragma unroll
      for (int j = 0; j < 4; j++) {
        int nf = nh * 4 + j;
        f16x8 b = *(const f16x8*)(sB + swz(nf * 16 + lm, s * 64 + lk * 16));
        acc[j] = __builtin_amdgcn_mfma_f32_16x16x32_f16(a, b, acc[j], 0, 0, 0);
      }
    }
  }
  __syncthreads();  // sAf reads done; reuse as h16 out-tile

  // ---- P4: epilogue: bn/relu -> h16 out-tile (first 16KB of sAf space)
  unsigned char* sOut = (unsigned char*)sAf;
#pragma unroll
  for (int j = 0; j < 4; j++) {
    int col = (nh * 4 + j) * 16 + lm;
    float blv = bl[col], scv = sc[col], shv = sh[col];
#pragma unroll
    for (int r_ = 0; r_ < 4; r_++) {
      float x = fmaf(acc[j][r_] + blv, scv, shv);
      h16 hv = (h16)fmaxf(x, 0.f);
      int rowl = rt * 16 + lk * 4 + r_;
      *(h16*)(sOut + swz(rowl, col * 2)) = hv;
    }
  }
  __syncthreads();

  // ---- P5: coalesced stores, 64B/thread (round-5 pattern)
  if (t < 256) {
    int r = t >> 2;
    int cs = (t & 3) * 64;  // byte offset in 256B row
    int row = base + r;
    if (row < M) {
#pragma unroll
      for (int q = 0; q < 4; q++) {
        f16x8 v = *(const f16x8*)(sOut + swz(r, cs + q * 16));
        *(f16x8*)(C + (size_t)row * Hv + (cs >> 1) + q * 8) = v;
      }
    }
  }
}

// out = relu(h @ W1 + b1) @ W2 + b2, h = [h_u ; h_t] virtual concat
__global__ __launch_bounds__(512, 4) void k_mlp(const h16* __restrict__ HU,
                                                const h16* __restrict__ HT,
                                                const h16* __restrict__ W1T,
                                                const float* __restrict__ b1,
                                                const float* __restrict__ W2,
                                                const float* __restrict__ b2,
                                                float* __restrict__ out, int Mtot) {
  __shared__ float y[128][65];                       // 33280 B
  __shared__ __align__(16) unsigned char sW[64 * 256];  // 16 KB, swizzled
  int t = threadIdx.x;
  int w = t >> 6, l = t & 63;
  int lm = l & 15, lk = l >> 4;

  // stage W1T (8192 h16) coalesced: thread t owns 16 h16
  {
    const h16* src = W1T + t * 16;
    f16x8 w0 = *(const f16x8*)(src + 0);
    f16x8 w1 = *(const f16x8*)(src + 8);
    int n = (t * 16) >> 7;
    int kb = ((t * 16) & 127) * 2;
    *(f16x8*)(sW + swz(n, kb + 0)) = w0;
    *(f16x8*)(sW + swz(n, kb + 16)) = w1;
  }

  int rowBase = blockIdx.x * 128 + w * 16;
  int ar = imin(rowBase + lm, Mtot - 1);
  const h16* arow =
      (ar < NUv) ? (HU + (size_t)ar * Hv) : (HT + (size_t)(ar - NUv) * Hv);
  f16x8 a0 = *(const f16x8*)(arow + 0 * 32 + lk * 8);
  f16x8 a1 = *(const f16x8*)(arow + 1 * 32 + lk * 8);
  f16x8 a2 = *(const f16x8*)(arow + 2 * 32 + lk * 8);
  f16x8 a3 = *(const f16x8*)(arow + 3 * 32 + lk * 8);
  __syncthreads();

  f32x4 acc[4];
#pragma unroll
  for (int nf = 0; nf < 4; nf++) acc[nf] = (f32x4){0.f, 0.f, 0.f, 0.f};
  {
    f16x8 as[4] = {a0, a1, a2, a3};
#pragma unroll
    for (int s = 0; s < 4; s++) {
#pragma unroll
      for (int nf = 0; nf < 4; nf++) {
        f16x8 b = *(const f16x8*)(sW + swz(nf * 16 + lm, s * 64 + lk * 16));
        acc[nf] = __builtin_amdgcn_mfma_f32_16x16x32_f16(as[s], b, acc[nf], 0, 0, 0);
      }
    }
  }
#pragma unroll
  for (int nf = 0; nf < 4; nf++) {
    int col = nf * 16 + lm;
    float b1v = b1[col];
#pragma unroll
    for (int r = 0; r < 4; r++) {
      int rloc = w * 16 + lk * 4 + r;
      y[rloc][col] = fmaxf(acc[nf][r] + b1v, 0.f);
    }
  }
  __syncthreads();
  if (t < 256) {
    int rloc = t >> 1, o = t & 1;
    int row = blockIdx.x * 128 + rloc;
    if (row < Mtot) {
      float sum = b2[o];
#pragma unroll
      for (int k = 0; k < HID2v; k++) sum += y[rloc][k] * W2[k * 2 + o];
      out[(size_t)row * 2 + o] = sum;
    }
  }
}

// ---------------------------------------------------------------- launcher
extern "C" void kernel_launch(void* const* d_in, const int* in_sizes, int n_in,
                              void* d_out, int out_size, void* d_ws, size_t ws_size,
                              hipStream_t stream) {
  (void)in_sizes; (void)n_in; (void)out_size;

  const int* x_user  = (const int*)d_in[0];
  const int* x_txn   = (const int*)d_in[1];
  const int* ei0_src = (const int*)d_in[2];
  const int* ei0_dst = (const int*)d_in[3];
  const int* ei1_src = (const int*)d_in[4];
  const int* ei1_dst = (const int*)d_in[5];
  const float* emb_user = (const float*)d_in[6];
  const float* emb_txn  = (const float*)d_in[7];
  const float* Wl = (const float*)d_in[8];
  const float* bl = (const float*)d_in[9];
  const float* Wr = (const float*)d_in[10];
  const float* bn_g = (const float*)d_in[11];
  const float* bn_b = (const float*)d_in[12];
  const float* bn_m = (const float*)d_in[13];
  const float* bn_v = (const float*)d_in[14];
  const float* W1 = (const float*)d_in[15];
  const float* b1 = (const float*)d_in[16];
  const float* W2 = (const float*)d_in[17];
  const float* b2 = (const float*)d_in[18];
  float* out = (float*)d_out;

  char* wsb;
  if (ws_size >= (size_t)WS_NEED) {
    wsb = (char*)d_ws;
  } else {
    void* sym = nullptr;
    hipGetSymbolAddress(&sym, HIP_SYMBOL(g_ws));
    wsb = (char*)sym;
  }
  size_t o = 0;
  auto alloc = [&](size_t bytes) -> void* {
    o = (o + 255) & ~(size_t)255;
    void* p = wsb + o;
    o += bytes;
    return p;
  };
  h16* hu   = (h16*)alloc((size_t)NUv * Hv * 2);   // in place
  h16* ht0  = (h16*)alloc((size_t)NTv * Hv * 2);   // double-buffered
  h16* ht1  = (h16*)alloc((size_t)NTv * Hv * 2);
  h16* WlT  = (h16*)alloc((size_t)NLv * 2 * Hv * Hv * 2);
  h16* WrT  = (h16*)alloc((size_t)NLv * 2 * Hv * Hv * 2);
  h16* W1T  = (h16*)alloc((size_t)HID2v * Hv * 2);
  float* bnsc = (float*)alloc((size_t)NLv * 2 * Hv * 4);
  float* bnsh = (float*)alloc((size_t)NLv * 2 * Hv * 4);
  int* off0 = (int*)alloc((size_t)(NTv + 1) * 4);
  int* off1 = (int*)alloc((size_t)(NUv + 1) * 4);
  int* cur0 = (int*)alloc((size_t)NTv * 4);
  int* cur1 = (int*)alloc((size_t)NUv * 4);
  int* ss0  = (int*)alloc((size_t)Ev * 4);
  int* ss1  = (int*)alloc((size_t)Ev * 4);
  int* bs0  = (int*)alloc(256 * 4);
  int* bs1  = (int*)alloc(256 * 4);

  const int G_E    = (Ev + 255) / 256;
  const int G_BS0  = (NTv + 2047) / 2048;        // 196
  const int G_BS1  = (NUv + 2047) / 2048;        // 49
  const int G_EMB  = ((NUv + NTv) * 16 + 255) / 256;
  const int G_WT   = (NLv * 2 * Hv * Hv + HID2v * Hv + 255) / 256;
  const int G_T    = (NTv + 63) / 64;            // 6250
  const int G_U    = (NUv + 63) / 64;            // 1563
  const int G_MLP  = (NUv + NTv + 127) / 128;    // 3907

  // 1. CSR build
  hipMemsetAsync(cur0, 0, (size_t)NTv * 4, stream);
  hipMemsetAsync(cur1, 0, (size_t)NUv * 4, stream);
  k_count<<<G_E, 256, 0, stream>>>(ei0_dst, ei1_dst, cur0, cur1, Ev);
  k_blocksum<<<G_BS0, 256, 0, stream>>>(cur0, bs0, NTv);
  k_blocksum<<<G_BS1, 256, 0, stream>>>(cur1, bs1, NUv);
  k_scansmall<<<1, 256, 0, stream>>>(bs0, G_BS0);
  k_scansmall<<<1, 256, 0, stream>>>(bs1, G_BS1);
  k_scanfinal<<<G_BS0, 256, 0, stream>>>(cur0, bs0, off0, cur0, NTv);
  k_scanfinal<<<G_BS1, 256, 0, stream>>>(cur1, bs1, off1, cur1, NUv);
  k_fill<<<G_E, 256, 0, stream>>>(ei0_src, ei0_dst, ei1_src, ei1_dst,
                                  cur0, cur1, ss0, ss1, Ev);

  // 2. weight conversion + bn prep
  k_wt<<<G_WT, 256, 0, stream>>>(Wl, Wr, W1, WlT, WrT, W1T);
  k_bn<<<3, 256, 0, stream>>>(bn_g, bn_b, bn_m, bn_v, bnsc, bnsh);

  // 3. embedding gather
  k_embed<<<G_EMB, 256, 0, stream>>>(x_user, x_txn, emb_user, emb_txn, hu, ht0);

  // 4. layers
  h16* ht_cur = ht0; h16* ht_nxt = ht1;
  for (int i = 0; i < NLv; i++) {
    const h16* WlT0 = WlT + (size_t)(i * 2 + 0) * Hv * Hv;
    const h16* WlT1 = WlT + (size_t)(i * 2 + 1) * Hv * Hv;
    const h16* WrT0 = WrT + (size_t)(i * 2 + 0) * Hv * Hv;
    const h16* WrT1 = WrT + (size_t)(i * 2 + 1) * Hv * Hv;
    const float* bl0 = bl + (size_t)(i * 2 + 0) * Hv;
    const float* bl1 = bl + (size_t)(i * 2 + 1) * Hv;
    const float* sc0 = bnsc + (size_t)(i * 2 + 0) * Hv;
    const float* sh0 = bnsh + (size_t)(i * 2 + 0) * Hv;
    const float* sc1 = bnsc + (size_t)(i * 2 + 1) * Hv;
    const float* sh1 = bnsh + (size_t)(i * 2 + 1) * Hv;

    // h_t' : agg over CSR0 (src=hu), dense=ht_cur -> ht_nxt ; bn[i,1], bl[i,0]
    k_fused<<<G_T, 512, 0, stream>>>(hu, ht_cur, off0, ss0, WlT0, WrT0,
                                     bl0, sc1, sh1, ht_nxt, NTv);
    // h_u' : agg over CSR1 (src=ht_cur OLD), dense=hu -> hu ; bn[i,0], bl[i,1]
    k_fused<<<G_U, 512, 0, stream>>>(ht_cur, hu, off1, ss1, WlT1, WrT1,
                                     bl1, sc0, sh0, hu, NUv);
    h16* tmp = ht_cur; ht_cur = ht_nxt; ht_nxt = tmp;
  }

  // 5. MLP head
  k_mlp<<<G_MLP, 512, 0, stream>>>(hu, ht_cur, W1T, b1, W2, b2, out, NUv + NTv);
}

// Round 8
// 660.355 us; speedup vs baseline: 3.3822x; 3.3822x over previous
//
#include <hip/hip_runtime.h>

// ---------------------------------------------------------------------------
// HeteroFraudGNN on MI355X — round 8: persistent-B grid-stride fused kernel.
// Reverts r7's edge-parallel LDS-atomic gather (32ms pathological dispatch).
// k_fused: grid=512 blocks x 512 thr; each block stages sB=[Wr|Wl] (K=256,
// 64KB, swizzled) ONCE, then grid-strides over 64-row tiles:
//   tile loop: {dense A-frag issue; row-centric gather (8thr/row, 2-deep
//   pipelined) -> sA} bar; {K=256 MFMA (16x64 wave tiles); bn/relu; direct
//   stores} bar.   -> 2 barriers/tile (r5 had 5), no per-tile B restage,
//   B-frag LDS reads 2KB/row (r5: 4KB/row).
// LDS 80KB -> 2 blocks/CU (16 waves). launch_bounds(512,4) caps VGPR 128.
// ---------------------------------------------------------------------------

#define NUv   100000
#define NTv   400000
#define Ev    400000
#define Hv    128
#define NLv   3
#define HID2v 64
#define EPSv  1e-5f

typedef _Float16 h16;
typedef __attribute__((ext_vector_type(8))) _Float16 f16x8;
typedef __attribute__((ext_vector_type(4))) float    f32x4;

#define WS_NEED (280u * 1024u * 1024u)
__device__ __attribute__((aligned(256))) static unsigned char g_ws[WS_NEED];

__device__ __forceinline__ int imin(int a, int b) { return a < b ? a : b; }
// swizzled byte offset, 256B rows (sA)
__device__ __forceinline__ int swz(int n, int kbyte) {
  return n * 256 + (kbyte ^ ((n & 7) << 4));
}
// swizzled byte offset, 512B rows (sB, K=256 layout: [Wr half | Wl half])
__device__ __forceinline__ int swzB(int n, int kbyte) {
  return n * 512 + (kbyte ^ ((n & 7) << 4));
}

// ---------------------------------------------------------------- CSR build
__global__ __launch_bounds__(256) void k_count(const int* __restrict__ d0,
                                               const int* __restrict__ d1,
                                               int* __restrict__ c0,
                                               int* __restrict__ c1, int e) {
  int t = blockIdx.x * 256 + threadIdx.x;
  if (t < e) {
    atomicAdd(c0 + d0[t], 1);
    atomicAdd(c1 + d1[t], 1);
  }
}

__global__ __launch_bounds__(256) void k_blocksum(const int* __restrict__ cnt,
                                                  int* __restrict__ bs, int n) {
  __shared__ int red[256];
  int base = blockIdx.x * 2048 + threadIdx.x * 8;
  int s = 0;
#pragma unroll
  for (int j = 0; j < 8; j++) {
    int p = base + j;
    if (p < n) s += cnt[p];
  }
  red[threadIdx.x] = s;
  __syncthreads();
  for (int st = 128; st > 0; st >>= 1) {
    if (threadIdx.x < st) red[threadIdx.x] += red[threadIdx.x + st];
    __syncthreads();
  }
  if (threadIdx.x == 0) bs[blockIdx.x] = red[0];
}

__global__ __launch_bounds__(256) void k_scansmall(int* __restrict__ bs, int g) {
  __shared__ int lds[256];
  int t = threadIdx.x;
  int v = (t < g) ? bs[t] : 0;
  lds[t] = v;
  __syncthreads();
  for (int st = 1; st < 256; st <<= 1) {
    int x = (t >= st) ? lds[t - st] : 0;
    __syncthreads();
    lds[t] += x;
    __syncthreads();
  }
  if (t < g) bs[t] = lds[t] - v;  // exclusive
}

__global__ __launch_bounds__(256) void k_scanfinal(const int* __restrict__ cnt,
                                                   const int* __restrict__ bs,
                                                   int* __restrict__ off,
                                                   int* __restrict__ cur, int n) {
  __shared__ int lds[256];
  int t = threadIdx.x;
  int base = blockIdx.x * 2048 + t * 8;
  int v[8], pre[8];
  int tsum = 0;
#pragma unroll
  for (int j = 0; j < 8; j++) {
    int p = base + j;
    v[j] = (p < n) ? cnt[p] : 0;
    pre[j] = tsum;
    tsum += v[j];
  }
  lds[t] = tsum;
  __syncthreads();
  for (int st = 1; st < 256; st <<= 1) {
    int x = (t >= st) ? lds[t - st] : 0;
    __syncthreads();
    lds[t] += x;
    __syncthreads();
  }
  int texcl = lds[t] - tsum;
  int boff = bs[blockIdx.x];
#pragma unroll
  for (int j = 0; j < 8; j++) {
    int p = base + j;
    if (p < n) {
      int o = boff + texcl + pre[j];
      off[p] = o;
      cur[p] = o;
      if (p == n - 1) off[n] = o + v[j];
    }
  }
}

__global__ __launch_bounds__(256) void k_fill(const int* __restrict__ s0,
                                              const int* __restrict__ d0,
                                              const int* __restrict__ s1,
                                              const int* __restrict__ d1,
                                              int* __restrict__ cur0,
                                              int* __restrict__ cur1,
                                              int* __restrict__ ss0,
                                              int* __restrict__ ss1, int e) {
  int t = blockIdx.x * 256 + threadIdx.x;
  if (t < e) {
    int p = atomicAdd(cur0 + d0[t], 1);
    ss0[p] = s0[t];
    int q = atomicAdd(cur1 + d1[t], 1);
    ss1[q] = s1[t];
  }
}

// ------------------------------------------------------- weight / bn prep
__global__ __launch_bounds__(256) void k_wt(const float* __restrict__ Wl,
                                            const float* __restrict__ Wr,
                                            const float* __restrict__ W1,
                                            h16* __restrict__ WlT,
                                            h16* __restrict__ WrT,
                                            h16* __restrict__ W1T) {
  int t = blockIdx.x * 256 + threadIdx.x;
  const int NW = NLv * 2 * Hv * Hv;  // 196608
  if (t < NW) {
    int mat = t / (Hv * Hv);
    int n = (t / Hv) % Hv;
    int k = t % Hv;
    WlT[t] = (h16)Wl[(size_t)mat * Hv * Hv + (size_t)k * Hv + n];
    WrT[t] = (h16)Wr[(size_t)mat * Hv * Hv + (size_t)k * Hv + n];
  } else if (t < NW + HID2v * Hv) {
    int u = t - NW;
    int n = u / Hv;
    int k = u % Hv;
    W1T[u] = (h16)W1[(size_t)k * HID2v + n];
  }
}

__global__ __launch_bounds__(256) void k_bn(const float* __restrict__ g,
                                            const float* __restrict__ b,
                                            const float* __restrict__ m,
                                            const float* __restrict__ v,
                                            float* __restrict__ sc,
                                            float* __restrict__ sh) {
  int t = blockIdx.x * 256 + threadIdx.x;
  if (t < NLv * 2 * Hv) {
    float inv = rsqrtf(v[t] + EPSv);
    float s = g[t] * inv;
    sc[t] = s;
    sh[t] = b[t] - m[t] * s;
  }
}

// ------------------------------------------------------------- embeddings
__global__ __launch_bounds__(256) void k_embed(const int* __restrict__ xu,
                                               const int* __restrict__ xt,
                                               const float* __restrict__ eu,
                                               const float* __restrict__ et,
                                               h16* __restrict__ hu,
                                               h16* __restrict__ ht) {
  int t = blockIdx.x * 256 + threadIdx.x;
  int row = t >> 4;
  int c = (t & 15) * 8;
  if (row >= NUv + NTv) return;
  const float* src;
  h16* dst;
  if (row < NUv) {
    src = eu + (size_t)xu[row] * Hv;
    dst = hu + (size_t)row * Hv;
  } else {
    int r2 = row - NUv;
    src = et + (size_t)xt[r2] * Hv;
    dst = ht + (size_t)r2 * Hv;
  }
  float4 v0 = *(const float4*)(src + c);
  float4 v1 = *(const float4*)(src + c + 4);
  f16x8 o;
  o[0] = (h16)v0.x; o[1] = (h16)v0.y; o[2] = (h16)v0.z; o[3] = (h16)v0.w;
  o[4] = (h16)v1.x; o[5] = (h16)v1.y; o[6] = (h16)v1.z; o[7] = (h16)v1.w;
  *(f16x8*)(dst + c) = o;
}

// --------------------------------------------------- fused gather+GEMM+bn
// OUT = relu(bn(seg_mean(SRC via off/ss) @ BTl + DENSE @ BTr + bl))
// mfma_f32_16x16x32_f16 convention (learn_hip m89):
//   A frag: a[j] = A[lane&15][kblk*32 + (lane>>4)*8 + j]
//   B frag: b[j] = B[kblk*32 + (lane>>4)*8 + j][lane&15]  (B^T stored [N][K])
//   D frag: d[r] = D[(lane>>4)*4 + r][lane&15]
// 8 waves: rg=w>>1 (16-row group of the 64-row tile), cg=w&1 (64-col half).
__global__ __launch_bounds__(512, 4) void k_fused(const h16* __restrict__ SRC,
                                                  const h16* __restrict__ DENSE,
                                                  const int* __restrict__ off,
                                                  const int* __restrict__ ss,
                                                  const h16* __restrict__ BTl,
                                                  const h16* __restrict__ BTr,
                                                  const float* __restrict__ bl,
                                                  const float* __restrict__ sc,
                                                  const float* __restrict__ sh,
                                                  h16* __restrict__ C, int M) {
  __shared__ __align__(16) unsigned char sB[128 * 512];  // 64 KB [Wr|Wl]
  __shared__ __align__(16) unsigned char sA[64 * 256];   // 16 KB gather tile

  int t = threadIdx.x;
  int l = t & 63;
  int lm = l & 15, lk = l >> 4;
  int w = t >> 6;
  int rg = w >> 1, cg = w & 1;

  // ---- stage sB ONCE: row n = [BTr_n (256B) | BTl_n (256B)], swizzled
  {
    int n = t >> 2;
    int kb = (t & 3) * 64;
    const h16* sr = BTr + t * 32;
    f16x8 r0 = *(const f16x8*)(sr + 0);
    f16x8 r1 = *(const f16x8*)(sr + 8);
    f16x8 r2 = *(const f16x8*)(sr + 16);
    f16x8 r3 = *(const f16x8*)(sr + 24);
    const h16* sl = BTl + t * 32;
    f16x8 l0 = *(const f16x8*)(sl + 0);
    f16x8 l1 = *(const f16x8*)(sl + 8);
    f16x8 l2 = *(const f16x8*)(sl + 16);
    f16x8 l3 = *(const f16x8*)(sl + 24);
    *(f16x8*)(sB + swzB(n, kb + 0)) = r0;
    *(f16x8*)(sB + swzB(n, kb + 16)) = r1;
    *(f16x8*)(sB + swzB(n, kb + 32)) = r2;
    *(f16x8*)(sB + swzB(n, kb + 48)) = r3;
    *(f16x8*)(sB + swzB(n, 256 + kb + 0)) = l0;
    *(f16x8*)(sB + swzB(n, 256 + kb + 16)) = l1;
    *(f16x8*)(sB + swzB(n, 256 + kb + 32)) = l2;
    *(f16x8*)(sB + swzB(n, 256 + kb + 48)) = l3;
  }
  __syncthreads();

  int nTiles = (M + 63) / 64;
  for (int tile = blockIdx.x; tile < nTiles; tile += gridDim.x) {
    int base = tile * 64;

    // ---- issue dense A-frags early (overlap with gather)
    int ar = imin(base + rg * 16 + lm, M - 1);
    const h16* arow = DENSE + (size_t)ar * Hv;
    f16x8 ad0 = *(const f16x8*)(arow + 0 * 32 + lk * 8);
    f16x8 ad1 = *(const f16x8*)(arow + 1 * 32 + lk * 8);
    f16x8 ad2 = *(const f16x8*)(arow + 2 * 32 + lk * 8);
    f16x8 ad3 = *(const f16x8*)(arow + 3 * 32 + lk * 8);

    // ---- gather seg_mean -> sA (8 thr/row, 16 h16 cols, 2-deep pipeline)
    {
      int r = t >> 3;
      int cs = (t & 7) * 16;
      float facc[16];
#pragma unroll
      for (int j = 0; j < 16; j++) facc[j] = 0.f;
      int row = base + r;
      if (row < M) {
        int e0 = off[row], e1 = off[row + 1];
        for (int e = e0; e < e1; e += 2) {
          int i0 = ss[e];
          bool v1 = (e + 1) < e1;
          int i1 = v1 ? ss[e + 1] : i0;
          const f16x8* p0 = (const f16x8*)(SRC + (size_t)i0 * Hv + cs);
          const f16x8* p1 = (const f16x8*)(SRC + (size_t)i1 * Hv + cs);
          f16x8 x0 = p0[0], x1 = p0[1];
          f16x8 y0 = p1[0], y1 = p1[1];
          float m1 = v1 ? 1.f : 0.f;
#pragma unroll
          for (int j = 0; j < 8; j++) {
            facc[j] += (float)x0[j];
            facc[8 + j] += (float)x1[j];
            facc[j] = fmaf((float)y0[j], m1, facc[j]);
            facc[8 + j] = fmaf((float)y1[j], m1, facc[8 + j]);
          }
        }
        int deg = e1 - e0;
        float inv = 1.f / (float)(deg > 1 ? deg : 1);
#pragma unroll
        for (int j = 0; j < 16; j++) facc[j] *= inv;
      }
#pragma unroll
      for (int q = 0; q < 2; q++) {
        f16x8 ov;
#pragma unroll
        for (int j = 0; j < 8; j++) ov[j] = (h16)facc[q * 8 + j];
        *(f16x8*)(sA + swz(r, cs * 2 + q * 16)) = ov;
      }
    }
    __syncthreads();  // bar1: sA ready

    // ---- K=256 MFMA: dense @ Wr (regs) + agg @ Wl (sA)
    f32x4 acc[4];
#pragma unroll
    for (int j = 0; j < 4; j++) acc[j] = (f32x4){0.f, 0.f, 0.f, 0.f};
    {
      f16x8 ads[4] = {ad0, ad1, ad2, ad3};
#pragma unroll
      for (int s = 0; s < 4; s++) {
#pragma unroll
        for (int j = 0; j < 4; j++) {
          int n = (cg * 4 + j) * 16 + lm;
          f16x8 b = *(const f16x8*)(sB + swzB(n, s * 64 + lk * 16));
          acc[j] = __builtin_amdgcn_mfma_f32_16x16x32_f16(ads[s], b, acc[j], 0, 0, 0);
        }
      }
#pragma unroll
      for (int s = 0; s < 4; s++) {
        f16x8 a = *(const f16x8*)(sA + swz(rg * 16 + lm, s * 64 + lk * 16));
#pragma unroll
        for (int j = 0; j < 4; j++) {
          int n = (cg * 4 + j) * 16 + lm;
          f16x8 b = *(const f16x8*)(sB + swzB(n, 256 + s * 64 + lk * 16));
          acc[j] = __builtin_amdgcn_mfma_f32_16x16x32_f16(a, b, acc[j], 0, 0, 0);
        }
      }
    }

    // ---- epilogue: bn/relu, direct stores (accepts ~1.4x write amp)
#pragma unroll
    for (int j = 0; j < 4; j++) {
      int col = (cg * 4 + j) * 16 + lm;
      float blv = bl[col], scv = sc[col], shv = sh[col];
#pragma unroll
      for (int r_ = 0; r_ < 4; r_++) {
        int row = base + rg * 16 + lk * 4 + r_;
        if (row < M) {
          float x = fmaf(acc[j][r_] + blv, scv, shv);
          C[(size_t)row * Hv + col] = (h16)fmaxf(x, 0.f);
        }
      }
    }
    __syncthreads();  // bar2: sA reads done before next tile's gather writes
  }
}

// out = relu(h @ W1 + b1) @ W2 + b2, h = [h_u ; h_t] virtual concat
__global__ __launch_bounds__(512, 4) void k_mlp(const h16* __restrict__ HU,
                                                const h16* __restrict__ HT,
                                                const h16* __restrict__ W1T,
                                                const float* __restrict__ b1,
                                                const float* __restrict__ W2,
                                                const float* __restrict__ b2,
                                                float* __restrict__ out, int Mtot) {
  __shared__ float y[128][65];                       // 33280 B
  __shared__ __align__(16) unsigned char sW[64 * 256];  // 16 KB, swizzled
  int t = threadIdx.x;
  int w = t >> 6, l = t & 63;
  int lm = l & 15, lk = l >> 4;

  // stage W1T (8192 h16) coalesced: thread t owns 16 h16
  {
    const h16* src = W1T + t * 16;
    f16x8 w0 = *(const f16x8*)(src + 0);
    f16x8 w1 = *(const f16x8*)(src + 8);
    int n = (t * 16) >> 7;
    int kb = ((t * 16) & 127) * 2;
    *(f16x8*)(sW + swz(n, kb + 0)) = w0;
    *(f16x8*)(sW + swz(n, kb + 16)) = w1;
  }

  int rowBase = blockIdx.x * 128 + w * 16;
  int ar = imin(rowBase + lm, Mtot - 1);
  const h16* arow =
      (ar < NUv) ? (HU + (size_t)ar * Hv) : (HT + (size_t)(ar - NUv) * Hv);
  f16x8 a0 = *(const f16x8*)(arow + 0 * 32 + lk * 8);
  f16x8 a1 = *(const f16x8*)(arow + 1 * 32 + lk * 8);
  f16x8 a2 = *(const f16x8*)(arow + 2 * 32 + lk * 8);
  f16x8 a3 = *(const f16x8*)(arow + 3 * 32 + lk * 8);
  __syncthreads();

  f32x4 acc[4];
#pragma unroll
  for (int nf = 0; nf < 4; nf++) acc[nf] = (f32x4){0.f, 0.f, 0.f, 0.f};
  {
    f16x8 as[4] = {a0, a1, a2, a3};
#pragma unroll
    for (int s = 0; s < 4; s++) {
#pragma unroll
      for (int nf = 0; nf < 4; nf++) {
        f16x8 b = *(const f16x8*)(sW + swz(nf * 16 + lm, s * 64 + lk * 16));
        acc[nf] = __builtin_amdgcn_mfma_f32_16x16x32_f16(as[s], b, acc[nf], 0, 0, 0);
      }
    }
  }
#pragma unroll
  for (int nf = 0; nf < 4; nf++) {
    int col = nf * 16 + lm;
    float b1v = b1[col];
#pragma unroll
    for (int r = 0; r < 4; r++) {
      int rloc = w * 16 + lk * 4 + r;
      y[rloc][col] = fmaxf(acc[nf][r] + b1v, 0.f);
    }
  }
  __syncthreads();
  if (t < 256) {
    int rloc = t >> 1, o = t & 1;
    int row = blockIdx.x * 128 + rloc;
    if (row < Mtot) {
      float sum = b2[o];
#pragma unroll
      for (int k = 0; k < HID2v; k++) sum += y[rloc][k] * W2[k * 2 + o];
      out[(size_t)row * 2 + o] = sum;
    }
  }
}

// ---------------------------------------------------------------- launcher
extern "C" void kernel_launch(void* const* d_in, const int* in_sizes, int n_in,
                              void* d_out, int out_size, void* d_ws, size_t ws_size,
                              hipStream_t stream) {
  (void)in_sizes; (void)n_in; (void)out_size;

  const int* x_user  = (const int*)d_in[0];
  const int* x_txn   = (const int*)d_in[1];
  const int* ei0_src = (const int*)d_in[2];
  const int* ei0_dst = (const int*)d_in[3];
  const int* ei1_src = (const int*)d_in[4];
  const int* ei1_dst = (const int*)d_in[5];
  const float* emb_user = (const float*)d_in[6];
  const float* emb_txn  = (const float*)d_in[7];
  const float* Wl = (const float*)d_in[8];
  const float* bl = (const float*)d_in[9];
  const float* Wr = (const float*)d_in[10];
  const float* bn_g = (const float*)d_in[11];
  const float* bn_b = (const float*)d_in[12];
  const float* bn_m = (const float*)d_in[13];
  const float* bn_v = (const float*)d_in[14];
  const float* W1 = (const float*)d_in[15];
  const float* b1 = (const float*)d_in[16];
  const float* W2 = (const float*)d_in[17];
  const float* b2 = (const float*)d_in[18];
  float* out = (float*)d_out;

  char* wsb;
  if (ws_size >= (size_t)WS_NEED) {
    wsb = (char*)d_ws;
  } else {
    void* sym = nullptr;
    hipGetSymbolAddress(&sym, HIP_SYMBOL(g_ws));
    wsb = (char*)sym;
  }
  size_t o = 0;
  auto alloc = [&](size_t bytes) -> void* {
    o = (o + 255) & ~(size_t)255;
    void* p = wsb + o;
    o += bytes;
    return p;
  };
  h16* hu   = (h16*)alloc((size_t)NUv * Hv * 2);   // in place
  h16* ht0  = (h16*)alloc((size_t)NTv * Hv * 2);   // double-buffered
  h16* ht1  = (h16*)alloc((size_t)NTv * Hv * 2);
  h16* WlT  = (h16*)alloc((size_t)NLv * 2 * Hv * Hv * 2);
  h16* WrT  = (h16*)alloc((size_t)NLv * 2 * Hv * Hv * 2);
  h16* W1T  = (h16*)alloc((size_t)HID2v * Hv * 2);
  float* bnsc = (float*)alloc((size_t)NLv * 2 * Hv * 4);
  float* bnsh = (float*)alloc((size_t)NLv * 2 * Hv * 4);
  int* off0 = (int*)alloc((size_t)(NTv + 1) * 4);
  int* off1 = (int*)alloc((size_t)(NUv + 1) * 4);
  int* cur0 = (int*)alloc((size_t)NTv * 4);
  int* cur1 = (int*)alloc((size_t)NUv * 4);
  int* ss0  = (int*)alloc((size_t)Ev * 4);
  int* ss1  = (int*)alloc((size_t)Ev * 4);
  int* bs0  = (int*)alloc(256 * 4);
  int* bs1  = (int*)alloc(256 * 4);

  const int G_E    = (Ev + 255) / 256;
  const int G_BS0  = (NTv + 2047) / 2048;        // 196
  const int G_BS1  = (NUv + 2047) / 2048;        // 49
  const int G_EMB  = ((NUv + NTv) * 16 + 255) / 256;
  const int G_WT   = (NLv * 2 * Hv * Hv + HID2v * Hv + 255) / 256;
  const int G_F    = 512;                        // persistent grid
  const int G_MLP  = (NUv + NTv + 127) / 128;    // 3907

  // 1. CSR build
  hipMemsetAsync(cur0, 0, (size_t)NTv * 4, stream);
  hipMemsetAsync(cur1, 0, (size_t)NUv * 4, stream);
  k_count<<<G_E, 256, 0, stream>>>(ei0_dst, ei1_dst, cur0, cur1, Ev);
  k_blocksum<<<G_BS0, 256, 0, stream>>>(cur0, bs0, NTv);
  k_blocksum<<<G_BS1, 256, 0, stream>>>(cur1, bs1, NUv);
  k_scansmall<<<1, 256, 0, stream>>>(bs0, G_BS0);
  k_scansmall<<<1, 256, 0, stream>>>(bs1, G_BS1);
  k_scanfinal<<<G_BS0, 256, 0, stream>>>(cur0, bs0, off0, cur0, NTv);
  k_scanfinal<<<G_BS1, 256, 0, stream>>>(cur1, bs1, off1, cur1, NUv);
  k_fill<<<G_E, 256, 0, stream>>>(ei0_src, ei0_dst, ei1_src, ei1_dst,
                                  cur0, cur1, ss0, ss1, Ev);

  // 2. weight conversion + bn prep
  k_wt<<<G_WT, 256, 0, stream>>>(Wl, Wr, W1, WlT, WrT, W1T);
  k_bn<<<3, 256, 0, stream>>>(bn_g, bn_b, bn_m, bn_v, bnsc, bnsh);

  // 3. embedding gather
  k_embed<<<G_EMB, 256, 0, stream>>>(x_user, x_txn, emb_user, emb_txn, hu, ht0);

  // 4. layers
  h16* ht_cur = ht0; h16* ht_nxt = ht1;
  for (int i = 0; i < NLv; i++) {
    const h16* WlT0 = WlT + (size_t)(i * 2 + 0) * Hv * Hv;
    const h16* WlT1 = WlT + (size_t)(i * 2 + 1) * Hv * Hv;
    const h16* WrT0 = WrT + (size_t)(i * 2 + 0) * Hv * Hv;
    const h16* WrT1 = WrT + (size_t)(i * 2 + 1) * Hv * Hv;
    const float* bl0 = bl + (size_t)(i * 2 + 0) * Hv;
    const float* bl1 = bl + (size_t)(i * 2 + 1) * Hv;
    const float* sc0 = bnsc + (size_t)(i * 2 + 0) * Hv;
    const float* sh0 = bnsh + (size_t)(i * 2 + 0) * Hv;
    const float* sc1 = bnsc + (size_t)(i * 2 + 1) * Hv;
    const float* sh1 = bnsh + (size_t)(i * 2 + 1) * Hv;

    // h_t' : agg over CSR0 (src=hu), dense=ht_cur -> ht_nxt ; bn[i,1], bl[i,0]
    k_fused<<<G_F, 512, 0, stream>>>(hu, ht_cur, off0, ss0, WlT0, WrT0,
                                     bl0, sc1, sh1, ht_nxt, NTv);
    // h_u' : agg over CSR1 (src=ht_cur OLD), dense=hu -> hu ; bn[i,0], bl[i,1]
    k_fused<<<G_F, 512, 0, stream>>>(ht_cur, hu, off1, ss1, WlT1, WrT1,
                                     bl1, sc0, sh0, hu, NUv);
    h16* tmp = ht_cur; ht_cur = ht_nxt; ht_nxt = tmp;
  }

  // 5. MLP head
  k_mlp<<<G_MLP, 512, 0, stream>>>(hu, ht_cur, W1T, b1, W2, b2, out, NUv + NTv);
}